// Round 5
// baseline (184.661 us; speedup 1.0000x reference)
//
#include <hip/hip_runtime.h>
#include <stdint.h>

typedef __bf16 bf16x8 __attribute__((ext_vector_type(8)));
typedef float f32x4 __attribute__((ext_vector_type(4)));
typedef short short8 __attribute__((ext_vector_type(8)));
typedef unsigned int uint2v __attribute__((ext_vector_type(2)));
typedef float float4_t __attribute__((ext_vector_type(4)));

union FragU { short8 s; bf16x8 b; };
union YbU { uint2v u2[2]; bf16x8 b; };

#define DEVI static __device__ __forceinline__

DEVI f32x4 mfma16(bf16x8 a, bf16x8 b, f32x4 c) {
  return __builtin_amdgcn_mfma_f32_16x16x32_bf16(a, b, c, 0, 0, 0);
}

DEVI bf16x8 cvt8(float4_t a, float4_t b) {
  bf16x8 r;
  r[0] = (__bf16)a[0]; r[1] = (__bf16)a[1]; r[2] = (__bf16)a[2]; r[3] = (__bf16)a[3];
  r[4] = (__bf16)b[0]; r[5] = (__bf16)b[1]; r[6] = (__bf16)b[2]; r[7] = (__bf16)b[3];
  return r;
}

// ---------------------------------------------------------------------------
// Kernel A (merged setup + encode). Block types by blockIdx.x:
//   [0, NBA)            : encode 64 rows of candidate_x -> HC, hcn
//   [NBA, NBA+NBB)      : encode 64 rows of x           -> H, hn
//   NB_ENC              : pad hcn[N..NP) = 1e30
//   NB_ENC+1 ...        : YT[16][NP] one-hot (16 * bpc blocks)
// Encoder: W (f32) staged f32->bf16 into LDS per block (XOR-swizzled);
// input loads issued BEFORE staging so HBM latency hides under it.
// ---------------------------------------------------------------------------
__global__ __launch_bounds__(256) void prep_encode_kernel(
    const float* __restrict__ cx, const float* __restrict__ x,
    const float* __restrict__ W, const float* __restrict__ bias,
    const int* __restrict__ y,
    unsigned short* __restrict__ HC, float* __restrict__ hcn,
    unsigned short* __restrict__ Hm, float* __restrict__ hnm,
    unsigned short* __restrict__ YT,
    int N, int Bm, int NP, int NBA, int NBB, int bpc) {
  __shared__ __align__(16) unsigned short Wl[128 * 128];  // 32 KB bf16

  const int bid = blockIdx.x, t = threadIdx.x;
  const int NB_ENC = NBA + NBB;

  if (bid >= NB_ENC) {
    if (bid == NB_ENC) {  // hcn pad
      int i = N + t;
      if (i < NP) hcn[i] = 1e30f;
    } else {  // YT one-hot
      int k = bid - NB_ENC - 1;
      int c = k / bpc, j = k - c * bpc;
      int n0 = j * 2048 + t * 8;
      unsigned short* dst = YT + (size_t)c * NP + n0;
#pragma unroll
      for (int e = 0; e < 8; ++e) {
        int n = n0 + e;
        if (n < NP) dst[e] = (n < N && y[n] == c) ? 0x3F80u : 0u;
      }
    }
    return;
  }

  const float* in;
  unsigned short* outh;
  float* outnorm;
  int M, blk;
  if (bid < NBA) {
    in = cx; outh = HC; outnorm = hcn; M = N; blk = bid;
  } else {
    in = x; outh = Hm; outnorm = hnm; M = Bm; blk = bid - NBA;
  }

  const int lane = t & 63, w = t >> 6;
  const int g = lane >> 4, q = lane & 15;
  const int rowbase = blk * 64 + w * 16;

  // 1. Issue input loads first (HBM) — consumed after the barrier.
  float4_t iv[8];
  const int arow = rowbase + q;
  const bool av = arow < M;
  {
    int ar = av ? arow : 0;
#pragma unroll
    for (int kc = 0; kc < 4; ++kc) {
      const float4_t* p = (const float4_t*)(in + (size_t)ar * 128 + kc * 32 + g * 8);
      iv[2 * kc] = p[0];
      iv[2 * kc + 1] = p[1];
    }
  }

  // 2. Stage W f32 -> bf16 into LDS (L2/L3-hit after first touch).
  {
    int row = t >> 1, half = t & 1;
    const float* wsrc = W + row * 128 + half * 64;
#pragma unroll
    for (int j = 0; j < 8; ++j) {
      float4_t v0 = *(const float4_t*)(wsrc + j * 8);
      float4_t v1 = *(const float4_t*)(wsrc + j * 8 + 4);
      FragU u; u.b = cvt8(v0, v1);
      int slot = (half * 8 + j) ^ (row & 7);
      *(short8*)((char*)Wl + row * 256 + slot * 16) = u.s;
    }
  }
  __syncthreads();

  // 3. Convert input to bf16 A-fragments.
  bf16x8 a[4];
#pragma unroll
  for (int kc = 0; kc < 4; ++kc) {
    FragU u; u.b = cvt8(iv[2 * kc], iv[2 * kc + 1]);
    if (!av) u.s = short8{0, 0, 0, 0, 0, 0, 0, 0};
    a[kc] = u.b;
  }

  // 4. MFMA: 8 col-tiles x 4 k-chunks, W frags from LDS.
  f32x4 acc[8];
#pragma unroll
  for (int nt = 0; nt < 8; ++nt) acc[nt] = f32x4{0.f, 0.f, 0.f, 0.f};
#pragma unroll
  for (int nt = 0; nt < 8; ++nt) {
    int brow = nt * 16 + q;
#pragma unroll
    for (int kc = 0; kc < 4; ++kc) {
      int slot = (kc * 4 + g) ^ (brow & 7);
      FragU u;
      u.s = *(const short8*)((const char*)Wl + brow * 256 + slot * 16);
      acc[nt] = mfma16(a[kc], u.b, acc[nt]);
    }
  }

  // 5. Epilogue: bias, round to bf16, store, sq-norm of ROUNDED value.
  float nsq[4] = {0.f, 0.f, 0.f, 0.f};
#pragma unroll
  for (int nt = 0; nt < 8; ++nt) {
    int col = nt * 16 + q;
    float bv = bias[col];
#pragma unroll
    for (int r = 0; r < 4; ++r) {
      int row = rowbase + g * 4 + r;  // D: row=(lane>>4)*4+reg, col=lane&15
      float val = acc[nt][r] + bv;
      __bf16 h = (__bf16)val;
      float vf = (float)h;
      nsq[r] += vf * vf;
      union { __bf16 h; unsigned short u; } cv; cv.h = h;
      if (row < M) outh[(size_t)row * 128 + col] = cv.u;
    }
  }
#pragma unroll
  for (int m = 1; m < 16; m <<= 1) {
#pragma unroll
    for (int r = 0; r < 4; ++r) nsq[r] += __shfl_xor(nsq[r], m, 64);
  }
  if (q == 0) {
#pragma unroll
    for (int r = 0; r < 4; ++r) {
      int row = rowbase + g * 4 + r;
      if (row < M) outnorm[row] = nsq[r];
    }
  }
}

// ---------------------------------------------------------------------------
// Main. Swapped QK (lane holds P[cand][hrow]); class-pool via second MFMA.
// Wave owns 32 H-rows (2 fragment sets). Partials -> part[row][chunk][16].
// ---------------------------------------------------------------------------
__global__ __launch_bounds__(512, 6) void nca_main(
    const unsigned short* __restrict__ H, const float* __restrict__ hnorm,
    const unsigned short* __restrict__ HC, const float* __restrict__ hcnorm,
    const unsigned short* __restrict__ YT, float* __restrict__ part,
    int B, int N, int NP, int NT, int CHUNKS) {
  __shared__ __align__(16) unsigned short HCl[2][64 * 128];  // 2 x 16 KB

  const int t = threadIdx.x, lane = t & 63, w = t >> 6;
  const int g = lane >> 4, q = lane & 15;
  const int rg = blockIdx.y, chunk = blockIdx.x;
  const int t0 = (int)(((long long)chunk * NT) / CHUNKS);
  const int t1 = (int)(((long long)(chunk + 1) * NT) / CHUNKS);

  bf16x8 hfrag[2][4];
  float hn[2];
  int hrow[2];
#pragma unroll
  for (int s = 0; s < 2; ++s) {
    hrow[s] = rg * 256 + s * 128 + w * 16 + q;
    bool v = hrow[s] < B;
    int ar = v ? hrow[s] : 0;
#pragma unroll
    for (int kc = 0; kc < 4; ++kc) {
      FragU u;
      u.s = *(const short8*)(H + (size_t)ar * 128 + kc * 32 + g * 8);
      if (!v) u.s = short8{0, 0, 0, 0, 0, 0, 0, 0};
      hfrag[s][kc] = u.b;
    }
    hn[s] = hnorm[ar];
  }

  f32x4 pool0 = f32x4{0.f, 0.f, 0.f, 0.f};
  f32x4 pool1 = f32x4{0.f, 0.f, 0.f, 0.f};

#define STAGE(TT, BUF)                                                        \
  {                                                                           \
    _Pragma("unroll") for (int i = 0; i < 2; ++i) {                           \
      int SI = t + 512 * i;                                                   \
      int row = SI >> 4, s = SI & 15;                                         \
      int srcslot = s ^ (row & 7);                                            \
      int cg = (TT)*64 + row;                                                 \
      if (cg >= N) cg = N - 1;                                                \
      const unsigned short* src = HC + (size_t)cg * 128 + srcslot * 8;        \
      char* ldsbase = (char*)HCl[BUF] + w * 1024 + i * 8192;                  \
      __builtin_amdgcn_global_load_lds(                                       \
          (const __attribute__((address_space(1))) unsigned int*)src,         \
          (__attribute__((address_space(3))) unsigned int*)ldsbase, 16, 0, 0);\
    }                                                                         \
  }

  int cur = 0;
  if (t0 < t1) STAGE(t0, 0);

  for (int tt = t0; tt < t1; ++tt) {
    __syncthreads();  // stage(tt) landed; prev tile reads drained
    if (tt + 1 < t1) STAGE(tt + 1, cur ^ 1);

    const int colbase = tt * 64;
    float4_t cnv[4];
    uint2v ytu[4];
#pragma unroll
    for (int ns = 0; ns < 4; ++ns) {
      cnv[ns] = *(const float4_t*)(hcnorm + colbase + ns * 16 + g * 4);
      ytu[ns] = *(const uint2v*)(YT + (size_t)q * NP + colbase + ns * 16 + g * 4);
    }

#pragma unroll
    for (int ns = 0; ns < 4; ++ns) {
      int brow = ns * 16 + q;
      f32x4 a0 = f32x4{0.f, 0.f, 0.f, 0.f};
      f32x4 a1 = f32x4{0.f, 0.f, 0.f, 0.f};
#pragma unroll
      for (int kc = 0; kc < 4; ++kc) {
        int slot = (kc * 4 + g) ^ (brow & 7);
        FragU u;
        u.s = *(const short8*)((const char*)HCl[cur] + brow * 256 + slot * 16);
        a0 = mfma16(u.b, hfrag[0][kc], a0);
        a1 = mfma16(u.b, hfrag[1][kc], a1);
      }
      FragU wb0, wb1;
      wb0.s = short8{0, 0, 0, 0, 0, 0, 0, 0};
      wb1.s = short8{0, 0, 0, 0, 0, 0, 0, 0};
#pragma unroll
      for (int r = 0; r < 4; ++r) {
        float d20 = fmaf(-2.f, a0[r], hn[0] + cnv[ns][r]);
        float d21 = fmaf(-2.f, a1[r], hn[1] + cnv[ns][r]);
        d20 = fmaxf(d20, 0.f);
        d21 = fmaxf(d21, 0.f);
        float di0 = __builtin_amdgcn_sqrtf(d20);
        float di1 = __builtin_amdgcn_sqrtf(d21);
        wb0.b[r] = (__bf16)__expf(0.f - di0);
        wb1.b[r] = (__bf16)__expf(0.f - di1);
      }
      YbU yb;
      yb.u2[0] = ytu[ns];
      yb.u2[1] = uint2v{0u, 0u};
      pool0 = mfma16(yb.b, wb0.b, pool0);
      pool1 = mfma16(yb.b, wb1.b, pool1);
    }
    cur ^= 1;
  }
#undef STAGE

  // part[row][chunk][16]: lane writes float4 at c = g*4.
  if (hrow[0] < B)
    *(f32x4*)(part + ((size_t)hrow[0] * CHUNKS + chunk) * 16 + g * 4) = pool0;
  if (hrow[1] < B)
    *(f32x4*)(part + ((size_t)hrow[1] * CHUNKS + chunk) * 16 + g * 4) = pool1;
}

// 4 rows per block (one wave each): sum partials (contiguous), softmax, log.
__global__ __launch_bounds__(256) void finalize_kernel(
    const float* __restrict__ part, float* __restrict__ out, int B,
    int CHUNKS) {
  const int w = threadIdx.x >> 6, t = threadIdx.x & 63;
  const int row = blockIdx.x * 4 + w;
  if (row >= B) return;
  const int c = t & 15, grp = t >> 4;
  const float* p = part + (size_t)row * CHUNKS * 16;
  float s = 0.f;
  for (int j = grp; j < CHUNKS; j += 4) s += p[j * 16 + c];
  s += __shfl_xor(s, 16, 64);
  s += __shfl_xor(s, 32, 64);
  float Z = 0.f;
#pragma unroll
  for (int cc = 0; cc < 10; ++cc) Z += __shfl(s, cc, 64);
  if (t < 10) out[row * 10 + t] = logf(fmaf(s, 1.f / Z, 1e-7f));
}

extern "C" void kernel_launch(void* const* d_in, const int* in_sizes, int n_in,
                              void* d_out, int out_size, void* d_ws,
                              size_t ws_size, hipStream_t stream) {
  const float* x = (const float*)d_in[0];
  const float* cx = (const float*)d_in[1];
  const int* cy = (const int*)d_in[2];
  const float* W = (const float*)d_in[3];
  const float* b = (const float*)d_in[4];
  const int B = in_sizes[0] / 128;
  const int N = in_sizes[1] / 128;
  float* out = (float*)d_out;

  const int NT = (N + 63) / 64;
  const int NP = NT * 64;
  const int RG = (B + 255) / 256;

  char* ws = (char*)d_ws;
  size_t o = 0;
  auto alloc = [&](size_t bytes) {
    size_t r = o;
    o += (bytes + 255) & ~(size_t)255;
    return r;
  };
  unsigned short* HC = (unsigned short*)(ws + alloc((size_t)N * 128 * 2));
  float* hcn = (float*)(ws + alloc((size_t)NP * 4));
  unsigned short* H = (unsigned short*)(ws + alloc((size_t)B * 128 * 2));
  float* hn = (float*)(ws + alloc((size_t)B * 4));
  unsigned short* YT = (unsigned short*)(ws + alloc((size_t)16 * NP * 2));

  // Partials: CHUNKS sized to workspace (cap 384, floor 32).
  size_t avail = (ws_size > o) ? (ws_size - o) : 0;
  int CHUNKS = (int)(avail / ((size_t)B * 16 * 4));
  if (CHUNKS > 384) CHUNKS = 384;
  if (CHUNKS < 32) CHUNKS = 32;
  float* part = (float*)(ws + alloc((size_t)CHUNKS * B * 16 * 4));

  const int NBA = (N + 63) / 64, NBB = (B + 63) / 64;
  const int bpc = (NP + 2047) / 2048;
  prep_encode_kernel<<<NBA + NBB + 1 + 16 * bpc, 256, 0, stream>>>(
      cx, x, W, b, cy, HC, hcn, H, hn, YT, N, B, NP, NBA, NBB, bpc);

  dim3 grid(CHUNKS, RG);
  nca_main<<<grid, 512, 0, stream>>>(H, hn, HC, hcn, YT, part, B, N, NP, NT,
                                     CHUNKS);
  finalize_kernel<<<(B + 3) / 4, 256, 0, stream>>>(part, out, B, CHUNKS);
}

// Round 6
// 162.272 us; speedup vs baseline: 1.1380x; 1.1380x over previous
//
#include <hip/hip_runtime.h>
#include <stdint.h>

typedef __bf16 bf16x8 __attribute__((ext_vector_type(8)));
typedef float f32x4 __attribute__((ext_vector_type(4)));
typedef short short8 __attribute__((ext_vector_type(8)));
typedef unsigned int uint2v __attribute__((ext_vector_type(2)));
typedef float float4_t __attribute__((ext_vector_type(4)));

#define LOG2E 1.44269504088896340736f

union FragU { short8 s; bf16x8 b; };
union YbU { uint2v u2[2]; bf16x8 b; };

#define DEVI static __device__ __forceinline__

DEVI f32x4 mfma16(bf16x8 a, bf16x8 b, f32x4 c) {
  return __builtin_amdgcn_mfma_f32_16x16x32_bf16(a, b, c, 0, 0, 0);
}

DEVI bf16x8 cvt8(float4_t a, float4_t b) {
  bf16x8 r;
  r[0] = (__bf16)a[0]; r[1] = (__bf16)a[1]; r[2] = (__bf16)a[2]; r[3] = (__bf16)a[3];
  r[4] = (__bf16)b[0]; r[5] = (__bf16)b[1]; r[6] = (__bf16)b[2]; r[7] = (__bf16)b[3];
  return r;
}

// ---------------------------------------------------------------------------
// Merged setup + encode. blockIdx.x ranges:
//   [0, NBA)       : encode 64 rows of candidate_x -> HC, hcn
//   [NBA, NBA+NBB) : encode 64 rows of x           -> H, hn
//   NB_ENC         : pad hcn[N..NP) = 1e30
//   NB_ENC+1 ...   : YT[16][NP] one-hot (16 * bpc blocks)
// Encoder output is PRE-SCALED by log2(e): h' = log2e * (x.W^T + b), rounded
// to bf16; norms on the rounded scaled values. Then exp(-dist) = exp2(-dist'),
// saving one VALU mul per pairwise element in nca_main.
// launch_bounds(256,3): enough VGPRs to keep all 24 loads in flight.
// ---------------------------------------------------------------------------
__global__ __launch_bounds__(256, 3) void prep_encode_kernel(
    const float* __restrict__ cx, const float* __restrict__ x,
    const float* __restrict__ W, const float* __restrict__ bias,
    const int* __restrict__ y,
    unsigned short* __restrict__ HC, float* __restrict__ hcn,
    unsigned short* __restrict__ Hm, float* __restrict__ hnm,
    unsigned short* __restrict__ YT,
    int N, int Bm, int NP, int NBA, int NBB, int bpc) {
  __shared__ __align__(16) unsigned short Wl[128 * 128];  // 32 KB bf16

  const int bid = blockIdx.x, t = threadIdx.x;
  const int NB_ENC = NBA + NBB;

  if (bid >= NB_ENC) {
    if (bid == NB_ENC) {  // hcn pad
      int i = N + t;
      if (i < NP) hcn[i] = 1e30f;
    } else {  // YT one-hot
      int k = bid - NB_ENC - 1;
      int c = k / bpc, j = k - c * bpc;
      int n0 = j * 2048 + t * 8;
      unsigned short* dst = YT + (size_t)c * NP + n0;
#pragma unroll
      for (int e = 0; e < 8; ++e) {
        int n = n0 + e;
        if (n < NP) dst[e] = (n < N && y[n] == c) ? 0x3F80u : 0u;
      }
    }
    return;
  }

  const float* in;
  unsigned short* outh;
  float* outnorm;
  int M, blk;
  if (bid < NBA) {
    in = cx; outh = HC; outnorm = hcn; M = N; blk = bid;
  } else {
    in = x; outh = Hm; outnorm = hnm; M = Bm; blk = bid - NBA;
  }

  const int lane = t & 63, w = t >> 6;
  const int g = lane >> 4, q = lane & 15;
  const int rowbase = blk * 64 + w * 16;

  // 1. Issue ALL input loads (HBM, longest latency) first.
  float4_t iv[8];
  const int arow = rowbase + q;
  const bool av = arow < M;
  {
    int ar = av ? arow : 0;
    const float* src = in + (size_t)ar * 128 + g * 8;
#pragma unroll
    for (int kc = 0; kc < 4; ++kc) {
      iv[2 * kc] = *(const float4_t*)(src + kc * 32);
      iv[2 * kc + 1] = *(const float4_t*)(src + kc * 32 + 4);
    }
  }

  // 2. Issue ALL W loads, then cvt + swizzled ds_write.
  {
    int row = t >> 1, half = t & 1;
    const float* wsrc = W + row * 128 + half * 64;
    float4_t wv[16];
#pragma unroll
    for (int j = 0; j < 16; ++j) wv[j] = *(const float4_t*)(wsrc + j * 4);
#pragma unroll
    for (int j = 0; j < 8; ++j) {
      FragU u; u.b = cvt8(wv[2 * j], wv[2 * j + 1]);
      int slot = (half * 8 + j) ^ (row & 7);
      *(short8*)((char*)Wl + row * 256 + slot * 16) = u.s;
    }
  }
  __syncthreads();

  // 3. Input -> bf16 A-fragments.
  bf16x8 a[4];
#pragma unroll
  for (int kc = 0; kc < 4; ++kc) {
    FragU u; u.b = cvt8(iv[2 * kc], iv[2 * kc + 1]);
    if (!av) u.s = short8{0, 0, 0, 0, 0, 0, 0, 0};
    a[kc] = u.b;
  }

  // 4. MFMA.
  f32x4 acc[8];
#pragma unroll
  for (int nt = 0; nt < 8; ++nt) acc[nt] = f32x4{0.f, 0.f, 0.f, 0.f};
#pragma unroll
  for (int nt = 0; nt < 8; ++nt) {
    int brow = nt * 16 + q;
#pragma unroll
    for (int kc = 0; kc < 4; ++kc) {
      int slot = (kc * 4 + g) ^ (brow & 7);
      FragU u;
      u.s = *(const short8*)((const char*)Wl + brow * 256 + slot * 16);
      acc[nt] = mfma16(a[kc], u.b, acc[nt]);
    }
  }

  // 5. Epilogue: bias, scale by log2e, round to bf16, sq-norm of ROUNDED.
  float nsq[4] = {0.f, 0.f, 0.f, 0.f};
#pragma unroll
  for (int nt = 0; nt < 8; ++nt) {
    int col = nt * 16 + q;
    float bv = bias[col];
#pragma unroll
    for (int r = 0; r < 4; ++r) {
      int row = rowbase + g * 4 + r;  // D: row=(lane>>4)*4+reg, col=lane&15
      float val = (acc[nt][r] + bv) * LOG2E;
      __bf16 h = (__bf16)val;
      float vf = (float)h;
      nsq[r] += vf * vf;
      union { __bf16 h; unsigned short u; } cv; cv.h = h;
      if (row < M) outh[(size_t)row * 128 + col] = cv.u;
    }
  }
#pragma unroll
  for (int m = 1; m < 16; m <<= 1) {
#pragma unroll
    for (int r = 0; r < 4; ++r) nsq[r] += __shfl_xor(nsq[r], m, 64);
  }
  if (q == 0) {
#pragma unroll
    for (int r = 0; r < 4; ++r) {
      int row = rowbase + g * 4 + r;
      if (row < M) outnorm[row] = nsq[r];
    }
  }
}

// ---------------------------------------------------------------------------
// Main. Swapped QK (lane holds P[cand][hrow]); class-pool via second MFMA.
// Wave owns 32 H-rows (2 fragment sets). All addressing hoisted out of the
// tile loop; per-element epilogue = add,fmaf,max + v_sqrt + v_exp2(-x) + cvt.
// Partials -> part[row][chunk][16]. launch_bounds(512,4): 128 VGPR, 2 blk/CU.
// ---------------------------------------------------------------------------
__global__ __launch_bounds__(512, 4) void nca_main(
    const unsigned short* __restrict__ H, const float* __restrict__ hnorm,
    const unsigned short* __restrict__ HC, const float* __restrict__ hcnorm,
    const unsigned short* __restrict__ YT, float* __restrict__ part,
    int B, int N, int NP, int NT, int CHUNKS) {
  __shared__ __align__(16) unsigned short HCl[2][64 * 128];  // 2 x 16 KB

  const int t = threadIdx.x, lane = t & 63, w = t >> 6;
  const int g = lane >> 4, q = lane & 15;
  const int rg = blockIdx.y, chunk = blockIdx.x;
  const int t0 = (int)(((long long)chunk * NT) / CHUNKS);
  const int t1 = (int)(((long long)(chunk + 1) * NT) / CHUNKS);

  bf16x8 hfrag[2][4];
  float hn[2];
  int hrow[2];
#pragma unroll
  for (int s = 0; s < 2; ++s) {
    hrow[s] = rg * 256 + s * 128 + w * 16 + q;
    bool v = hrow[s] < B;
    int ar = v ? hrow[s] : 0;
#pragma unroll
    for (int kc = 0; kc < 4; ++kc) {
      FragU u;
      u.s = *(const short8*)(H + (size_t)ar * 128 + kc * 32 + g * 8);
      if (!v) u.s = short8{0, 0, 0, 0, 0, 0, 0, 0};
      hfrag[s][kc] = u.b;
    }
    hn[s] = hnorm[ar];
  }

  // Hoisted LDS read offsets: addr(ns,kc) = soff[kc] + ns*4096 (+ buf*16384).
  // (brow&7) == (q&7) since ns*16 is 0 mod 8.
  int soff[4];
#pragma unroll
  for (int kc = 0; kc < 4; ++kc)
    soff[kc] = q * 256 + (((kc * 4 + g) ^ (q & 7)) << 4);

  // Hoisted stage offsets (srcslot identical for both 8KB halves: 32 % 8 == 0).
  const int srow = t >> 4;                       // 0..31
  const int sslot = (t & 15) ^ (srow & 7);
  const int g_off = srow * 256 + sslot * 16;     // byte offset inside tile
  const int l_off = w * 1024;                    // wave-uniform LDS offset
  const char* HCc = (const char*)HC;

  f32x4 pool0 = f32x4{0.f, 0.f, 0.f, 0.f};
  f32x4 pool1 = f32x4{0.f, 0.f, 0.f, 0.f};

  // Tail tiles read past HC's end (<=16KB) into the adjacent ws region —
  // harmless; padded columns are killed by YT==0.
#define STAGE(TT, BUF)                                                         \
  {                                                                            \
    const char* src = HCc + (size_t)(TT)*16384 + g_off;                        \
    char* lb = (char*)HCl[BUF] + l_off;                                        \
    __builtin_amdgcn_global_load_lds(                                          \
        (const __attribute__((address_space(1))) unsigned int*)src,            \
        (__attribute__((address_space(3))) unsigned int*)lb, 16, 0, 0);        \
    __builtin_amdgcn_global_load_lds(                                          \
        (const __attribute__((address_space(1))) unsigned int*)(src + 8192),   \
        (__attribute__((address_space(3))) unsigned int*)(lb + 8192), 16, 0,   \
        0);                                                                    \
  }

  int cur = 0;
  if (t0 < t1) STAGE(t0, 0);

  for (int tt = t0; tt < t1; ++tt) {
    __syncthreads();  // stage(tt) landed; prev-tile LDS reads drained
    if (tt + 1 < t1) STAGE(tt + 1, cur ^ 1);

    const int colbase = tt * 64;
    float4_t cnv[4];
    uint2v ytu[4];
#pragma unroll
    for (int ns = 0; ns < 4; ++ns) {
      cnv[ns] = *(const float4_t*)(hcnorm + colbase + ns * 16 + g * 4);
      ytu[ns] = *(const uint2v*)(YT + (size_t)q * NP + colbase + ns * 16 + g * 4);
    }

    // Whole-tile QK MFMAs first (fat independent block)...
    const char* lb = (const char*)HCl[cur];
    f32x4 a0[4], a1[4];
#pragma unroll
    for (int ns = 0; ns < 4; ++ns) {
      a0[ns] = f32x4{0.f, 0.f, 0.f, 0.f};
      a1[ns] = f32x4{0.f, 0.f, 0.f, 0.f};
    }
#pragma unroll
    for (int ns = 0; ns < 4; ++ns) {
#pragma unroll
      for (int kc = 0; kc < 4; ++kc) {
        FragU u;
        u.s = *(const short8*)(lb + soff[kc] + ns * 4096);
        a0[ns] = mfma16(u.b, hfrag[0][kc], a0[ns]);
        a1[ns] = mfma16(u.b, hfrag[1][kc], a1[ns]);
      }
    }

    // ...then the whole-tile epilogue (VALU/trans overlaps other waves' MFMA).
#pragma unroll
    for (int ns = 0; ns < 4; ++ns) {
      FragU wb0, wb1;
      wb0.s = short8{0, 0, 0, 0, 0, 0, 0, 0};
      wb1.s = short8{0, 0, 0, 0, 0, 0, 0, 0};
#pragma unroll
      for (int r = 0; r < 4; ++r) {
        float c0 = hn[0] + cnv[ns][r];
        float c1 = hn[1] + cnv[ns][r];
        float d20 = fmaxf(fmaf(-2.f, a0[ns][r], c0), 0.f);
        float d21 = fmaxf(fmaf(-2.f, a1[ns][r], c1), 0.f);
        float di0 = __builtin_amdgcn_sqrtf(d20);
        float di1 = __builtin_amdgcn_sqrtf(d21);
        wb0.b[r] = (__bf16)__builtin_amdgcn_exp2f(-di0);
        wb1.b[r] = (__bf16)__builtin_amdgcn_exp2f(-di1);
      }
      YbU yb;
      yb.u2[0] = ytu[ns];
      yb.u2[1] = uint2v{0u, 0u};
      pool0 = mfma16(yb.b, wb0.b, pool0);
      pool1 = mfma16(yb.b, wb1.b, pool1);
    }
    cur ^= 1;
  }
#undef STAGE

  // part[row][chunk][16]: lane writes float4 at c = g*4.
  if (hrow[0] < B)
    *(f32x4*)(part + ((size_t)hrow[0] * CHUNKS + chunk) * 16 + g * 4) = pool0;
  if (hrow[1] < B)
    *(f32x4*)(part + ((size_t)hrow[1] * CHUNKS + chunk) * 16 + g * 4) = pool1;
}

// 4 rows per block (one wave each): sum partials (contiguous), softmax, log.
__global__ __launch_bounds__(256) void finalize_kernel(
    const float* __restrict__ part, float* __restrict__ out, int B,
    int CHUNKS) {
  const int w = threadIdx.x >> 6, t = threadIdx.x & 63;
  const int row = blockIdx.x * 4 + w;
  if (row >= B) return;
  const int c = t & 15, grp = t >> 4;
  const float* p = part + (size_t)row * CHUNKS * 16;
  float s = 0.f;
  for (int j = grp; j < CHUNKS; j += 4) s += p[j * 16 + c];
  s += __shfl_xor(s, 16, 64);
  s += __shfl_xor(s, 32, 64);
  float Z = 0.f;
#pragma unroll
  for (int cc = 0; cc < 10; ++cc) Z += __shfl(s, cc, 64);
  if (t < 10) out[row * 10 + t] = logf(fmaf(s, 1.f / Z, 1e-7f));
}

extern "C" void kernel_launch(void* const* d_in, const int* in_sizes, int n_in,
                              void* d_out, int out_size, void* d_ws,
                              size_t ws_size, hipStream_t stream) {
  const float* x = (const float*)d_in[0];
  const float* cx = (const float*)d_in[1];
  const int* cy = (const int*)d_in[2];
  const float* W = (const float*)d_in[3];
  const float* b = (const float*)d_in[4];
  const int B = in_sizes[0] / 128;
  const int N = in_sizes[1] / 128;
  float* out = (float*)d_out;

  const int NT = (N + 63) / 64;
  const int NP = NT * 64;
  const int RG = (B + 255) / 256;

  char* ws = (char*)d_ws;
  size_t o = 0;
  auto alloc = [&](size_t bytes) {
    size_t r = o;
    o += (bytes + 255) & ~(size_t)255;
    return r;
  };
  unsigned short* HC = (unsigned short*)(ws + alloc((size_t)N * 128 * 2));
  float* hcn = (float*)(ws + alloc((size_t)NP * 4 + 16384));  // +16KB overrun pad
  unsigned short* H = (unsigned short*)(ws + alloc((size_t)B * 128 * 2));
  float* hn = (float*)(ws + alloc((size_t)B * 4));
  unsigned short* YT = (unsigned short*)(ws + alloc((size_t)16 * NP * 2));

  // Partials: CHUNKS sized to workspace (cap 256 -> 2 blocks/CU with RG=2).
  size_t avail = (ws_size > o) ? (ws_size - o) : 0;
  int CHUNKS = (int)(avail / ((size_t)B * 16 * 4));
  if (CHUNKS > 256) CHUNKS = 256;
  if (CHUNKS < 32) CHUNKS = 32;
  float* part = (float*)(ws + alloc((size_t)CHUNKS * B * 16 * 4));

  const int NBA = (N + 63) / 64, NBB = (B + 63) / 64;
  const int bpc = (NP + 2047) / 2048;
  prep_encode_kernel<<<NBA + NBB + 1 + 16 * bpc, 256, 0, stream>>>(
      cx, x, W, b, cy, HC, hcn, H, hn, YT, N, B, NP, NBA, NBB, bpc);

  dim3 grid(CHUNKS, RG);
  nca_main<<<grid, 512, 0, stream>>>(H, hn, HC, hcn, YT, part, B, N, NP, NT,
                                     CHUNKS);
  finalize_kernel<<<(B + 3) / 4, 256, 0, stream>>>(part, out, B, CHUNKS);
}

// Round 7
// 161.326 us; speedup vs baseline: 1.1446x; 1.0059x over previous
//
#include <hip/hip_runtime.h>
#include <stdint.h>

typedef __bf16 bf16x8 __attribute__((ext_vector_type(8)));
typedef float f32x4 __attribute__((ext_vector_type(4)));
typedef short short8 __attribute__((ext_vector_type(8)));
typedef unsigned int uint2v __attribute__((ext_vector_type(2)));
typedef float float4_t __attribute__((ext_vector_type(4)));

#define LOG2E 1.44269504088896340736f

union FragU { short8 s; bf16x8 b; };
union YbU { uint2v u2[2]; bf16x8 b; };

#define DEVI static __device__ __forceinline__

DEVI f32x4 mfma16(bf16x8 a, bf16x8 b, f32x4 c) {
  return __builtin_amdgcn_mfma_f32_16x16x32_bf16(a, b, c, 0, 0, 0);
}

DEVI bf16x8 cvt8(float4_t a, float4_t b) {
  bf16x8 r;
  r[0] = (__bf16)a[0]; r[1] = (__bf16)a[1]; r[2] = (__bf16)a[2]; r[3] = (__bf16)a[3];
  r[4] = (__bf16)b[0]; r[5] = (__bf16)b[1]; r[6] = (__bf16)b[2]; r[7] = (__bf16)b[3];
  return r;
}

// ---------------------------------------------------------------------------
// Merged setup + encode. blockIdx.x ranges:
//   [0, NBA)       : encode 128 rows of candidate_x -> HC, hcn
//   [NBA, NBA+NBB) : encode 128 rows of x           -> H, hn
//   NB_ENC         : pad hcn[N..NP) = 1e30
//   NB_ENC+1 ...   : YT[16][NP] one-hot (16 * bpc blocks)
// 128 rows/block (2 fragment sets per wave): W staged once per 128 rows,
// each LDS W-fragment read feeds 2 MFMAs. Output pre-scaled by log2(e).
// ---------------------------------------------------------------------------
__global__ __launch_bounds__(256, 3) void prep_encode_kernel(
    const float* __restrict__ cx, const float* __restrict__ x,
    const float* __restrict__ W, const float* __restrict__ bias,
    const int* __restrict__ y,
    unsigned short* __restrict__ HC, float* __restrict__ hcn,
    unsigned short* __restrict__ Hm, float* __restrict__ hnm,
    unsigned short* __restrict__ YT,
    int N, int Bm, int NP, int NBA, int NBB, int bpc) {
  __shared__ __align__(16) unsigned short Wl[128 * 128];  // 32 KB bf16

  const int bid = blockIdx.x, t = threadIdx.x;
  const int NB_ENC = NBA + NBB;

  if (bid >= NB_ENC) {
    if (bid == NB_ENC) {  // hcn pad
      int i = N + t;
      if (i < NP) hcn[i] = 1e30f;
    } else {  // YT one-hot
      int k = bid - NB_ENC - 1;
      int c = k / bpc, j = k - c * bpc;
      int n0 = j * 2048 + t * 8;
      unsigned short* dst = YT + (size_t)c * NP + n0;
#pragma unroll
      for (int e = 0; e < 8; ++e) {
        int n = n0 + e;
        if (n < NP) dst[e] = (n < N && y[n] == c) ? 0x3F80u : 0u;
      }
    }
    return;
  }

  const float* in;
  unsigned short* outh;
  float* outnorm;
  int M, blk;
  if (bid < NBA) {
    in = cx; outh = HC; outnorm = hcn; M = N; blk = bid;
  } else {
    in = x; outh = Hm; outnorm = hnm; M = Bm; blk = bid - NBA;
  }

  const int lane = t & 63, w = t >> 6;
  const int g = lane >> 4, q = lane & 15;
  const int rb = blk * 128 + w * 16;  // set s rows: rb + s*64 + {g*4..}

  // 1. Issue ALL input loads (HBM, longest latency) first: 2 rowsets.
  float4_t iv[2][8];
  int arow[2];
  bool av[2];
#pragma unroll
  for (int s = 0; s < 2; ++s) {
    arow[s] = rb + s * 64 + q;
    av[s] = arow[s] < M;
    int ar = av[s] ? arow[s] : 0;
    const float* src = in + (size_t)ar * 128 + g * 8;
#pragma unroll
    for (int kc = 0; kc < 4; ++kc) {
      iv[s][2 * kc] = *(const float4_t*)(src + kc * 32);
      iv[s][2 * kc + 1] = *(const float4_t*)(src + kc * 32 + 4);
    }
  }

  // 2. Issue ALL W loads, then cvt + swizzled ds_write.
  {
    int row = t >> 1, half = t & 1;
    const float* wsrc = W + row * 128 + half * 64;
    float4_t wv[16];
#pragma unroll
    for (int j = 0; j < 16; ++j) wv[j] = *(const float4_t*)(wsrc + j * 4);
#pragma unroll
    for (int j = 0; j < 8; ++j) {
      FragU u; u.b = cvt8(wv[2 * j], wv[2 * j + 1]);
      int slot = (half * 8 + j) ^ (row & 7);
      *(short8*)((char*)Wl + row * 256 + slot * 16) = u.s;
    }
  }
  __syncthreads();

  // 3. Inputs -> bf16 A-fragments.
  bf16x8 a[2][4];
#pragma unroll
  for (int s = 0; s < 2; ++s)
#pragma unroll
    for (int kc = 0; kc < 4; ++kc) {
      FragU u; u.b = cvt8(iv[s][2 * kc], iv[s][2 * kc + 1]);
      if (!av[s]) u.s = short8{0, 0, 0, 0, 0, 0, 0, 0};
      a[s][kc] = u.b;
    }

  // 4. MFMA: each W fragment read feeds both rowsets.
  f32x4 acc[2][8];
#pragma unroll
  for (int s = 0; s < 2; ++s)
#pragma unroll
    for (int nt = 0; nt < 8; ++nt) acc[s][nt] = f32x4{0.f, 0.f, 0.f, 0.f};
#pragma unroll
  for (int nt = 0; nt < 8; ++nt) {
    int brow = nt * 16 + q;
#pragma unroll
    for (int kc = 0; kc < 4; ++kc) {
      int slot = (kc * 4 + g) ^ (brow & 7);
      FragU u;
      u.s = *(const short8*)((const char*)Wl + brow * 256 + slot * 16);
      acc[0][nt] = mfma16(a[0][kc], u.b, acc[0][nt]);
      acc[1][nt] = mfma16(a[1][kc], u.b, acc[1][nt]);
    }
  }

  // 5. Epilogue: bias, scale log2e, round to bf16, sq-norm of ROUNDED value.
  float nsq[2][4] = {{0.f, 0.f, 0.f, 0.f}, {0.f, 0.f, 0.f, 0.f}};
#pragma unroll
  for (int nt = 0; nt < 8; ++nt) {
    int col = nt * 16 + q;
    float bv = bias[col];
#pragma unroll
    for (int s = 0; s < 2; ++s) {
#pragma unroll
      for (int r = 0; r < 4; ++r) {
        int row = rb + s * 64 + g * 4 + r;  // D: row=(lane>>4)*4+reg
        float val = (acc[s][nt][r] + bv) * LOG2E;
        __bf16 h = (__bf16)val;
        float vf = (float)h;
        nsq[s][r] += vf * vf;
        union { __bf16 h; unsigned short u; } cv; cv.h = h;
        if (row < M) outh[(size_t)row * 128 + col] = cv.u;
      }
    }
  }
#pragma unroll
  for (int m = 1; m < 16; m <<= 1) {
#pragma unroll
    for (int s = 0; s < 2; ++s)
#pragma unroll
      for (int r = 0; r < 4; ++r) nsq[s][r] += __shfl_xor(nsq[s][r], m, 64);
  }
  if (q == 0) {
#pragma unroll
    for (int s = 0; s < 2; ++s)
#pragma unroll
      for (int r = 0; r < 4; ++r) {
        int row = rb + s * 64 + g * 4 + r;
        if (row < M) outnorm[row] = nsq[s][r];
      }
  }
}

// ---------------------------------------------------------------------------
// Main. Swapped QK (lane holds P[cand][hrow]); class-pool via second MFMA.
// 3-buffer LDS, 2-tiles-ahead prefetch, counted vmcnt (never 0 mid-loop):
//   iter tt: s_waitcnt vmcnt(2) [stage(tt) landed, stage(tt+1) in flight]
//            s_barrier; issue cnv/ytu(tt); issue STAGE(tt+2); compute.
// Overwrite-safety: buf (tt+2)%3 was read at iter tt-1, all waves passed
// this iteration's barrier since. cnv/ytu are issued BEFORE the new STAGE so
// the epilogue's implicit vmcnt wait (in-order counter) keeps it in flight.
// ---------------------------------------------------------------------------
__global__ __launch_bounds__(512, 4) void nca_main(
    const unsigned short* __restrict__ H, const float* __restrict__ hnorm,
    const unsigned short* __restrict__ HC, const float* __restrict__ hcnorm,
    const unsigned short* __restrict__ YT, float* __restrict__ part,
    int B, int N, int NP, int NT, int CHUNKS) {
  __shared__ __align__(16) unsigned short HCl[3 * 64 * 128];  // 48 KB

  const int t = threadIdx.x, lane = t & 63, w = t >> 6;
  const int g = lane >> 4, q = lane & 15;
  const int rg = blockIdx.y, chunk = blockIdx.x;
  const int t0 = (int)(((long long)chunk * NT) / CHUNKS);
  const int t1 = (int)(((long long)(chunk + 1) * NT) / CHUNKS);

  bf16x8 hfrag[2][4];
  float hn[2];
  int hrow[2];
#pragma unroll
  for (int s = 0; s < 2; ++s) {
    hrow[s] = rg * 256 + s * 128 + w * 16 + q;
    bool v = hrow[s] < B;
    int ar = v ? hrow[s] : 0;
#pragma unroll
    for (int kc = 0; kc < 4; ++kc) {
      FragU u;
      u.s = *(const short8*)(H + (size_t)ar * 128 + kc * 32 + g * 8);
      if (!v) u.s = short8{0, 0, 0, 0, 0, 0, 0, 0};
      hfrag[s][kc] = u.b;
    }
    hn[s] = hnorm[ar];
  }

  // Hoisted LDS read offsets: addr(ns,kc) = soff[kc] + ns*4096 + buf*16384.
  int soff[4];
#pragma unroll
  for (int kc = 0; kc < 4; ++kc)
    soff[kc] = q * 256 + (((kc * 4 + g) ^ (q & 7)) << 4);

  // Hoisted stage offsets.
  const int srow = t >> 4;                    // 0..31
  const int sslot = (t & 15) ^ (srow & 7);
  const int g_off = srow * 256 + sslot * 16;  // byte offset inside tile
  const int l_off = w * 1024;                 // wave-uniform LDS offset
  const char* HCc = (const char*)HC;

  f32x4 pool0 = f32x4{0.f, 0.f, 0.f, 0.f};
  f32x4 pool1 = f32x4{0.f, 0.f, 0.f, 0.f};

#define STAGE(TT, BI)                                                          \
  {                                                                            \
    const char* src_ = HCc + (size_t)(TT)*16384 + g_off;                       \
    char* lb_ = (char*)HCl + (BI)*16384 + l_off;                               \
    __builtin_amdgcn_global_load_lds(                                          \
        (const __attribute__((address_space(1))) unsigned int*)src_,           \
        (__attribute__((address_space(3))) unsigned int*)lb_, 16, 0, 0);       \
    __builtin_amdgcn_global_load_lds(                                          \
        (const __attribute__((address_space(1))) unsigned int*)(src_ + 8192),  \
        (__attribute__((address_space(3))) unsigned int*)(lb_ + 8192), 16, 0,  \
        0);                                                                    \
  }

  if (t0 < t1) STAGE(t0, 0);
  if (t0 + 1 < t1) STAGE(t0 + 1, 1);

  int bi = 0;  // buffer holding tile tt
  for (int tt = t0; tt < t1; ++tt) {
    // stage(tt) must have landed; keep stage(tt+1) in flight if it exists.
    if (tt + 1 < t1) {
      asm volatile("s_waitcnt vmcnt(2)" ::: "memory");
    } else {
      asm volatile("s_waitcnt vmcnt(0)" ::: "memory");
    }
    __builtin_amdgcn_s_barrier();
    __builtin_amdgcn_sched_barrier(0);

    const int colbase = tt * 64;
    // cnv/ytu issued BEFORE the prefetch STAGE (older in vmcnt order).
    float4_t cnv[4];
    uint2v ytu[4];
#pragma unroll
    for (int ns = 0; ns < 4; ++ns) {
      cnv[ns] = *(const float4_t*)(hcnorm + colbase + ns * 16 + g * 4);
      ytu[ns] = *(const uint2v*)(YT + (size_t)q * NP + colbase + ns * 16 + g * 4);
    }
    __builtin_amdgcn_sched_barrier(0);

    int bs = bi + 2; if (bs >= 3) bs -= 3;
    if (tt + 2 < t1) STAGE(tt + 2, bs);

    const char* lb = (const char*)HCl + bi * 16384;
    // ns-groups of 2: 16 MFMAs per group, bounded register pressure.
#pragma unroll
    for (int nsg = 0; nsg < 2; ++nsg) {
      f32x4 a0[2], a1[2];
#pragma unroll
      for (int k = 0; k < 2; ++k) {
        a0[k] = f32x4{0.f, 0.f, 0.f, 0.f};
        a1[k] = f32x4{0.f, 0.f, 0.f, 0.f};
      }
#pragma unroll
      for (int k = 0; k < 2; ++k) {
        int ns = nsg * 2 + k;
#pragma unroll
        for (int kc = 0; kc < 4; ++kc) {
          FragU u;
          u.s = *(const short8*)(lb + soff[kc] + ns * 4096);
          a0[k] = mfma16(u.b, hfrag[0][kc], a0[k]);
          a1[k] = mfma16(u.b, hfrag[1][kc], a1[k]);
        }
      }
#pragma unroll
      for (int k = 0; k < 2; ++k) {
        int ns = nsg * 2 + k;
        FragU wb0, wb1;
        wb0.s = short8{0, 0, 0, 0, 0, 0, 0, 0};
        wb1.s = short8{0, 0, 0, 0, 0, 0, 0, 0};
#pragma unroll
        for (int r = 0; r < 4; ++r) {
          float c0 = hn[0] + cnv[ns][r];
          float c1 = hn[1] + cnv[ns][r];
          float d20 = fmaxf(fmaf(-2.f, a0[k][r], c0), 0.f);
          float d21 = fmaxf(fmaf(-2.f, a1[k][r], c1), 0.f);
          float di0 = __builtin_amdgcn_sqrtf(d20);
          float di1 = __builtin_amdgcn_sqrtf(d21);
          wb0.b[r] = (__bf16)__builtin_amdgcn_exp2f(-di0);
          wb1.b[r] = (__bf16)__builtin_amdgcn_exp2f(-di1);
        }
        YbU yb;
        yb.u2[0] = ytu[ns];
        yb.u2[1] = uint2v{0u, 0u};
        pool0 = mfma16(yb.b, wb0.b, pool0);
        pool1 = mfma16(yb.b, wb1.b, pool1);
      }
    }
    ++bi; if (bi == 3) bi = 0;
  }
#undef STAGE

  // part[row][chunk][16]: lane writes float4 at c = g*4.
  if (hrow[0] < B)
    *(f32x4*)(part + ((size_t)hrow[0] * CHUNKS + chunk) * 16 + g * 4) = pool0;
  if (hrow[1] < B)
    *(f32x4*)(part + ((size_t)hrow[1] * CHUNKS + chunk) * 16 + g * 4) = pool1;
}

// 4 rows per block (one wave each): sum partials (contiguous), softmax, log.
__global__ __launch_bounds__(256) void finalize_kernel(
    const float* __restrict__ part, float* __restrict__ out, int B,
    int CHUNKS) {
  const int w = threadIdx.x >> 6, t = threadIdx.x & 63;
  const int row = blockIdx.x * 4 + w;
  if (row >= B) return;
  const int c = t & 15, grp = t >> 4;
  const float* p = part + (size_t)row * CHUNKS * 16;
  float s = 0.f;
  for (int j = grp; j < CHUNKS; j += 4) s += p[j * 16 + c];
  s += __shfl_xor(s, 16, 64);
  s += __shfl_xor(s, 32, 64);
  float Z = 0.f;
#pragma unroll
  for (int cc = 0; cc < 10; ++cc) Z += __shfl(s, cc, 64);
  if (t < 10) out[row * 10 + t] = logf(fmaf(s, 1.f / Z, 1e-7f));
}

extern "C" void kernel_launch(void* const* d_in, const int* in_sizes, int n_in,
                              void* d_out, int out_size, void* d_ws,
                              size_t ws_size, hipStream_t stream) {
  const float* x = (const float*)d_in[0];
  const float* cx = (const float*)d_in[1];
  const int* cy = (const int*)d_in[2];
  const float* W = (const float*)d_in[3];
  const float* b = (const float*)d_in[4];
  const int B = in_sizes[0] / 128;
  const int N = in_sizes[1] / 128;
  float* out = (float*)d_out;

  const int NT = (N + 63) / 64;
  const int NP = NT * 64;
  const int RG = (B + 255) / 256;

  char* ws = (char*)d_ws;
  size_t o = 0;
  auto alloc = [&](size_t bytes) {
    size_t r = o;
    o += (bytes + 255) & ~(size_t)255;
    return r;
  };
  unsigned short* HC = (unsigned short*)(ws + alloc((size_t)N * 128 * 2));
  float* hcn = (float*)(ws + alloc((size_t)NP * 4 + 16384));  // +16KB overrun pad
  unsigned short* H = (unsigned short*)(ws + alloc((size_t)B * 128 * 2));
  float* hn = (float*)(ws + alloc((size_t)B * 4));
  unsigned short* YT = (unsigned short*)(ws + alloc((size_t)16 * NP * 2));

  // Partials: CHUNKS sized to workspace (cap 256 -> 2 blocks/CU with RG=2).
  size_t avail = (ws_size > o) ? (ws_size - o) : 0;
  int CHUNKS = (int)(avail / ((size_t)B * 16 * 4));
  if (CHUNKS > 256) CHUNKS = 256;
  if (CHUNKS < 32) CHUNKS = 32;
  float* part = (float*)(ws + alloc((size_t)CHUNKS * B * 16 * 4));

  const int NBA = (N + 127) / 128, NBB = (B + 127) / 128;
  const int bpc = (NP + 2047) / 2048;
  prep_encode_kernel<<<NBA + NBB + 1 + 16 * bpc, 256, 0, stream>>>(
      cx, x, W, b, cy, HC, hcn, H, hn, YT, N, B, NP, NBA, NBB, bpc);

  dim3 grid(CHUNKS, RG);
  nca_main<<<grid, 512, 0, stream>>>(H, hn, HC, hcn, YT, part, B, N, NP, NT,
                                     CHUNKS);
  finalize_kernel<<<(B + 3) / 4, 256, 0, stream>>>(part, out, B, CHUNKS);
}